// Round 8
// baseline (178.926 us; speedup 1.0000x reference)
//
#include <hip/hip_runtime.h>

#define N 1024
#define D 128

// ---------------- proj: Q,K,A,B = z@{Wq,Wk,W1a,W1b} (+biases; b1 folded into A; 1/sqrt(D) folded into Q) ----------------
__global__ __launch_bounds__(256) void proj_kernel(
    const float* __restrict__ z,
    const float* __restrict__ Wq, const float* __restrict__ bq,
    const float* __restrict__ Wk, const float* __restrict__ bk,
    const float* __restrict__ W1, const float* __restrict__ b1,
    float* __restrict__ Q, float* __restrict__ Kx,
    float* __restrict__ A, float* __restrict__ B)
{
    const int d  = threadIdx.x & (D - 1);
    const int h  = threadIdx.x >> 7;              // wave-uniform: 0 -> Q/K, 1 -> A/B
    const int r0 = blockIdx.x * 8;
    const float* __restrict__ Wa = h ? W1           : Wq;
    const float* __restrict__ Wb = h ? (W1 + D * D) : Wk;

    float acc0[8] = {0,0,0,0,0,0,0,0};
    float acc1[8] = {0,0,0,0,0,0,0,0};

    for (int c = 0; c < D / 4; ++c) {
        float4 zr[8];
#pragma unroll
        for (int r = 0; r < 8; ++r)
            zr[r] = *(const float4*)&z[(r0 + r) * D + c * 4];
#pragma unroll
        for (int q = 0; q < 4; ++q) {
            const int k = c * 4 + q;
            const float wa = Wa[k * D + d];
            const float wb = Wb[k * D + d];
#pragma unroll
            for (int r = 0; r < 8; ++r) {
                const float zv = (q == 0) ? zr[r].x : (q == 1) ? zr[r].y : (q == 2) ? zr[r].z : zr[r].w;
                acc0[r] = fmaf(zv, wa, acc0[r]);
                acc1[r] = fmaf(zv, wb, acc1[r]);
            }
        }
    }
    if (h == 0) {
        const float c0 = bq[d], c1 = bk[d];
        const float scale = 0.08838834764831845f;   // 1/sqrt(128), folded into Q
#pragma unroll
        for (int r = 0; r < 8; ++r) {
            Q [(r0 + r) * D + d] = (acc0[r] + c0) * scale;
            Kx[(r0 + r) * D + d] = acc1[r] + c1;
        }
    } else {
        const float c0 = b1[d];
#pragma unroll
        for (int r = 0; r < 8; ++r) {
            A[(r0 + r) * D + d] = acc0[r] + c0;
            B[(r0 + r) * D + d] = acc1[r];
        }
    }
}

// ---------------- FUSED scores + softmax + top-32: S never leaves LDS ----------------
// Block = 4 waves = 4 rows. K staged tile-wise (64 j x 128 d, pitch 132 dwords -> bank-balanced,
// 16B aligned). Each wave computes its row's 64 scores per tile (lane = j), keeps the row in
// LDS Ss[w][1024], then runs the proven wave-level top-32 selection and writes adjacency.
#define KP 132

__global__ __launch_bounds__(256) void scoretopk_kernel(
    const float* __restrict__ Q, const float* __restrict__ Kx,
    const float* __restrict__ dist, float* __restrict__ adj)
{
    __shared__ float Ks[64 * KP];      // 33.8 KB
    __shared__ float Qs[4 * KP];       // 2.1 KB
    __shared__ float Ss[4 * 1024];     // 16 KB
    const int tid  = threadIdx.x;
    const int lane = tid & 63;
    const int w    = tid >> 6;
    const int i0   = blockIdx.x * 4;

    if (tid < 128) {
        const int row = tid >> 5, c = tid & 31;
        *(float4*)&Qs[row * KP + c * 4] = *(const float4*)&Q[(size_t)(i0 + row) * D + c * 4];
    }

    for (int t = 0; t < 16; ++t) {
        __syncthreads();               // protect Ks from previous tile's readers
#pragma unroll
        for (int p = 0; p < 8; ++p) {
            const int e = p * 256 + tid;           // 2048 float4 chunks: 64 rows x 32
            const int row = e >> 5, c = e & 31;
            *(float4*)&Ks[row * KP + c * 4] = *(const float4*)&Kx[(size_t)(t * 64 + row) * D + c * 4];
        }
        __syncthreads();

        float acc = 0.f;
#pragma unroll 8
        for (int c = 0; c < 32; ++c) {
            const float4 q4 = *(const float4*)&Qs[w * KP + c * 4];      // broadcast
            const float4 k4 = *(const float4*)&Ks[lane * KP + c * 4];
            acc = fmaf(q4.x, k4.x, acc);
            acc = fmaf(q4.y, k4.y, acc);
            acc = fmaf(q4.z, k4.z, acc);
            acc = fmaf(q4.w, k4.w, acc);
        }
        const int j = t * 64 + lane;
        Ss[w * 1024 + j] = acc * __expf(-dist[(size_t)(i0 + w) * N + j]);
    }

    // ---- per-wave softmax + top-32 on own row (no barrier needed: own-wave data) ----
    const float* sr = &Ss[w * 1024];
    float v[16];
#pragma unroll
    for (int c = 0; c < 4; ++c) {
        const float4 f = *(const float4*)&sr[(c * 64 + lane) * 4];
        v[c * 4 + 0] = f.x; v[c * 4 + 1] = f.y; v[c * 4 + 2] = f.z; v[c * 4 + 3] = f.w;
    }
    float m = v[0];
#pragma unroll
    for (int e = 1; e < 16; ++e) m = fmaxf(m, v[e]);
#pragma unroll
    for (int off = 1; off < 64; off <<= 1) m = fmaxf(m, __shfl_xor(m, off));
    float sum = 0.f;
#pragma unroll
    for (int e = 0; e < 16; ++e) sum += __expf(v[e] - m);
#pragma unroll
    for (int off = 1; off < 64; off <<= 1) sum += __shfl_xor(sum, off);
    const float inv = 1.0f / sum;

    unsigned long long key[16];
#pragma unroll
    for (int e = 0; e < 16; ++e) {
        const int j = (((e >> 2) * 64 + lane) * 4) + (e & 3);
        unsigned u = __float_as_uint(v[e]);
        u = (u & 0x80000000u) ? ~u : (u | 0x80000000u);
        key[e] = ((unsigned long long)u << 32) | (unsigned)(N - 1 - j);
    }
    unsigned flags = 0;
    for (int it = 0; it < 32; ++it) {
        unsigned long long best = key[0];
#pragma unroll
        for (int e = 1; e < 16; ++e) best = (key[e] > best) ? key[e] : best;
#pragma unroll
        for (int off = 1; off < 64; off <<= 1) {
            const unsigned long long o = __shfl_xor(best, off);
            if (o > best) best = o;
        }
#pragma unroll
        for (int e = 0; e < 16; ++e)
            if (key[e] == best) { flags |= 1u << e; key[e] = 0ull; }
    }
    float* ar = adj + (size_t)(i0 + w) * N;
#pragma unroll
    for (int c = 0; c < 4; ++c) {
        float4 o;
        o.x = (flags & (1u << (c * 4 + 0))) ? __expf(v[c * 4 + 0] - m) * inv : 0.f;
        o.y = (flags & (1u << (c * 4 + 1))) ? __expf(v[c * 4 + 1] - m) * inv : 0.f;
        o.z = (flags & (1u << (c * 4 + 2))) ? __expf(v[c * 4 + 2] - m) * inv : 0.f;
        o.w = (flags & (1u << (c * 4 + 3))) ? __expf(v[c * 4 + 3] - m) * inv : 0.f;
        *(float4*)&ar[(c * 64 + lane) * 4] = o;
    }
}

// ---------------- pairwise gelu classifier + 3-way softmax ----------------
// 32x32 tile, d-split (17.4 KB LDS), 2x2 micro-tile PACKED over (i0,i1) as float2
// -> v_pk_{add,mul,fma}_f32 halve VALU issue slots; exp2/rcp stay scalar (trans pipe).
// Same formulas/constants as r7 (numerically identical).
__device__ __forceinline__ float2 fast_gelu2(float2 x) {
    float2 u, t, r;
    u.x = x.x * x.x;                        u.y = x.y * x.y;
    t.x = x.x * fmaf(-0.1029434f, u.x, -2.3022082f);
    t.y = x.y * fmaf(-0.1029434f, u.y, -2.3022082f);
    r.x = __builtin_amdgcn_rcpf(1.0f + __builtin_amdgcn_exp2f(t.x));
    r.y = __builtin_amdgcn_rcpf(1.0f + __builtin_amdgcn_exp2f(t.y));
    return make_float2(x.x * r.x, x.y * r.y);
}

__global__ __launch_bounds__(256) void pair_kernel(
    const float* __restrict__ A, const float* __restrict__ B,
    const float* __restrict__ W2, const float* __restrict__ b2,
    float* __restrict__ out)
{
    __shared__ float As[32 * 17 * 4];   // [row][chunk] pitch 17 float4
    __shared__ float Bs[32 * 17 * 4];
    const int tid = threadIdx.x;
    const int bi = blockIdx.y * 32, bj = blockIdx.x * 32;
    const int tx = tid & 15, ty = tid >> 4;

    const float bb0 = b2[0], bb1 = b2[1], bb2 = b2[2];
    float2 accP[2][3];                  // [jj][class], packed over (i0, i1)
#pragma unroll
    for (int jj = 0; jj < 2; ++jj) {
        accP[jj][0] = make_float2(bb0, bb0);
        accP[jj][1] = make_float2(bb1, bb1);
        accP[jj][2] = make_float2(bb2, bb2);
    }

    const float4* As4 = (const float4*)As;
    const float4* Bs4 = (const float4*)Bs;

    for (int kk = 0; kk < D; kk += 64) {
        __syncthreads();
#pragma unroll
        for (int t = 0; t < 2; ++t) {
            const int e = t * 256 + tid;       // 512 chunks: 32 rows x 16 float4-cols
            const int row = e >> 4, c = e & 15;
            *(float4*)&As[(row * 17 + c) * 4] = *(const float4*)&A[(size_t)(bi + row) * D + kk + c * 4];
            *(float4*)&Bs[(row * 17 + c) * 4] = *(const float4*)&B[(size_t)(bj + row) * D + kk + c * 4];
        }
        __syncthreads();

#pragma unroll 4
        for (int c = 0; c < 16; ++c) {
            const float4 a0 = As4[ty * 17 + c];
            const float4 a1 = As4[(ty + 16) * 17 + c];
            const float4 b0 = Bs4[tx * 17 + c];
            const float4 b1 = Bs4[(tx + 16) * 17 + c];
#pragma unroll
            for (int q = 0; q < 4; ++q) {
                const int dd = kk + c * 4 + q;
                const float w0 = W2[dd * 3 + 0];    // wave-uniform -> s_load
                const float w1 = W2[dd * 3 + 1];
                const float w2 = W2[dd * 3 + 2];
                float2 av;
                av.x = (q == 0) ? a0.x : (q == 1) ? a0.y : (q == 2) ? a0.z : a0.w;
                av.y = (q == 0) ? a1.x : (q == 1) ? a1.y : (q == 2) ? a1.z : a1.w;
                const float bv0 = (q == 0) ? b0.x : (q == 1) ? b0.y : (q == 2) ? b0.z : b0.w;
                const float bv1 = (q == 0) ? b1.x : (q == 1) ? b1.y : (q == 2) ? b1.z : b1.w;
                float2 x0, x1;
                x0.x = av.x + bv0;  x0.y = av.y + bv0;
                x1.x = av.x + bv1;  x1.y = av.y + bv1;
                const float2 g0 = fast_gelu2(x0);
                const float2 g1 = fast_gelu2(x1);
                accP[0][0].x = fmaf(g0.x, w0, accP[0][0].x); accP[0][0].y = fmaf(g0.y, w0, accP[0][0].y);
                accP[0][1].x = fmaf(g0.x, w1, accP[0][1].x); accP[0][1].y = fmaf(g0.y, w1, accP[0][1].y);
                accP[0][2].x = fmaf(g0.x, w2, accP[0][2].x); accP[0][2].y = fmaf(g0.y, w2, accP[0][2].y);
                accP[1][0].x = fmaf(g1.x, w0, accP[1][0].x); accP[1][0].y = fmaf(g1.y, w0, accP[1][0].y);
                accP[1][1].x = fmaf(g1.x, w1, accP[1][1].x); accP[1][1].y = fmaf(g1.y, w1, accP[1][1].y);
                accP[1][2].x = fmaf(g1.x, w2, accP[1][2].x); accP[1][2].y = fmaf(g1.y, w2, accP[1][2].y);
            }
        }
    }

#pragma unroll
    for (int ii = 0; ii < 2; ++ii)
#pragma unroll
        for (int jj = 0; jj < 2; ++jj) {
            const int i = bi + ty + 16 * ii;
            const int j = bj + tx + 16 * jj;
            const float l0 = ii ? accP[jj][0].y : accP[jj][0].x;
            const float l1 = ii ? accP[jj][1].y : accP[jj][1].x;
            const float l2 = ii ? accP[jj][2].y : accP[jj][2].x;
            const float mm = fmaxf(l0, fmaxf(l1, l2));
            const float e0 = __expf(l0 - mm), e1 = __expf(l1 - mm), e2 = __expf(l2 - mm);
            const float inv2 = 1.0f / (e0 + e1 + e2);
            float* o = out + ((size_t)i * N + j) * 3;
            o[0] = e0 * inv2; o[1] = e1 * inv2; o[2] = e2 * inv2;
        }
}

extern "C" void kernel_launch(void* const* d_in, const int* in_sizes, int n_in,
                              void* d_out, int out_size, void* d_ws, size_t ws_size,
                              hipStream_t stream)
{
    const float* z    = (const float*)d_in[0];
    const float* dist = (const float*)d_in[1];
    const float* Wq   = (const float*)d_in[2];
    const float* bq   = (const float*)d_in[3];
    const float* Wk   = (const float*)d_in[4];
    const float* bk   = (const float*)d_in[5];
    const float* W1   = (const float*)d_in[6];
    const float* b1   = (const float*)d_in[7];
    const float* W2   = (const float*)d_in[8];
    const float* b2   = (const float*)d_in[9];

    float* out = (float*)d_out;
    float* ws  = (float*)d_ws;
    float* Q  = ws;
    float* K  = ws + (size_t)N * D;
    float* A  = ws + 2 * (size_t)N * D;
    float* B  = ws + 3 * (size_t)N * D;

    proj_kernel<<<N / 8, 256, 0, stream>>>(z, Wq, bq, Wk, bk, W1, b1, Q, K, A, B);
    scoretopk_kernel<<<N / 4, 256, 0, stream>>>(Q, K, dist, out);
    pair_kernel<<<dim3(N / 32, N / 32), 256, 0, stream>>>(A, B, W2, b2, out + (size_t)N * N);
}

// Round 9
// 162.947 us; speedup vs baseline: 1.0981x; 1.0981x over previous
//
#include <hip/hip_runtime.h>

#define N 1024
#define D 128

typedef float v2f __attribute__((ext_vector_type(2)));

// ---------------- proj: Q,K,A,B = z@{Wq,Wk,W1a,W1b} (+biases; b1 folded into A; 1/sqrt(D) folded into Q) ----------------
__global__ __launch_bounds__(256) void proj_kernel(
    const float* __restrict__ z,
    const float* __restrict__ Wq, const float* __restrict__ bq,
    const float* __restrict__ Wk, const float* __restrict__ bk,
    const float* __restrict__ W1, const float* __restrict__ b1,
    float* __restrict__ Q, float* __restrict__ Kx,
    float* __restrict__ A, float* __restrict__ B)
{
    const int d  = threadIdx.x & (D - 1);
    const int h  = threadIdx.x >> 7;              // wave-uniform: 0 -> Q/K, 1 -> A/B
    const int r0 = blockIdx.x * 8;
    const float* __restrict__ Wa = h ? W1           : Wq;
    const float* __restrict__ Wb = h ? (W1 + D * D) : Wk;

    float acc0[8] = {0,0,0,0,0,0,0,0};
    float acc1[8] = {0,0,0,0,0,0,0,0};

    for (int c = 0; c < D / 4; ++c) {
        float4 zr[8];
#pragma unroll
        for (int r = 0; r < 8; ++r)
            zr[r] = *(const float4*)&z[(r0 + r) * D + c * 4];
#pragma unroll
        for (int q = 0; q < 4; ++q) {
            const int k = c * 4 + q;
            const float wa = Wa[k * D + d];
            const float wb = Wb[k * D + d];
#pragma unroll
            for (int r = 0; r < 8; ++r) {
                const float zv = (q == 0) ? zr[r].x : (q == 1) ? zr[r].y : (q == 2) ? zr[r].z : zr[r].w;
                acc0[r] = fmaf(zv, wa, acc0[r]);
                acc1[r] = fmaf(zv, wb, acc1[r]);
            }
        }
    }
    if (h == 0) {
        const float c0 = bq[d], c1 = bk[d];
        const float scale = 0.08838834764831845f;   // 1/sqrt(128), folded into Q
#pragma unroll
        for (int r = 0; r < 8; ++r) {
            Q [(r0 + r) * D + d] = (acc0[r] + c0) * scale;
            Kx[(r0 + r) * D + d] = acc1[r] + c1;
        }
    } else {
        const float c0 = b1[d];
#pragma unroll
        for (int r = 0; r < 8; ++r) {
            A[(r0 + r) * D + d] = acc0[r] + c0;
            B[(r0 + r) * D + d] = acc1[r];
        }
    }
}

// ---------------- scores: S = (Q K^T) * exp(-dist), 32x32 tile (r7 known-good) ----------------
__global__ __launch_bounds__(256) void score_kernel(
    const float* __restrict__ Q, const float* __restrict__ Kx,
    const float* __restrict__ dist, float* __restrict__ S)
{
    __shared__ float Qs[32 * 33 * 4];
    __shared__ float Ks[32 * 33 * 4];
    const int tid = threadIdx.x;
    const int bi = blockIdx.y * 32, bj = blockIdx.x * 32;
    const int tx = tid & 15, ty = tid >> 4;

#pragma unroll
    for (int t = 0; t < 4; ++t) {
        const int e = t * 256 + tid;
        const int row = e >> 5, c = e & 31;
        *(float4*)&Qs[(row * 33 + c) * 4] = *(const float4*)&Q [(size_t)(bi + row) * D + c * 4];
        *(float4*)&Ks[(row * 33 + c) * 4] = *(const float4*)&Kx[(size_t)(bj + row) * D + c * 4];
    }
    __syncthreads();

    const float4* Qs4 = (const float4*)Qs;
    const float4* Ks4 = (const float4*)Ks;
    float a00 = 0.f, a01 = 0.f, a10 = 0.f, a11 = 0.f;

#pragma unroll 4
    for (int c = 0; c < 32; ++c) {
        const float4 q0 = Qs4[ty * 33 + c];
        const float4 q1 = Qs4[(ty + 16) * 33 + c];
        const float4 k0 = Ks4[tx * 33 + c];
        const float4 k1 = Ks4[(tx + 16) * 33 + c];
        a00 = fmaf(q0.x, k0.x, a00); a00 = fmaf(q0.y, k0.y, a00); a00 = fmaf(q0.z, k0.z, a00); a00 = fmaf(q0.w, k0.w, a00);
        a01 = fmaf(q0.x, k1.x, a01); a01 = fmaf(q0.y, k1.y, a01); a01 = fmaf(q0.z, k1.z, a01); a01 = fmaf(q0.w, k1.w, a01);
        a10 = fmaf(q1.x, k0.x, a10); a10 = fmaf(q1.y, k0.y, a10); a10 = fmaf(q1.z, k0.z, a10); a10 = fmaf(q1.w, k0.w, a10);
        a11 = fmaf(q1.x, k1.x, a11); a11 = fmaf(q1.y, k1.y, a11); a11 = fmaf(q1.z, k1.z, a11); a11 = fmaf(q1.w, k1.w, a11);
    }

    const int i0 = bi + ty, i1 = bi + ty + 16;
    const int j0 = bj + tx, j1 = bj + tx + 16;
    S[(size_t)i0 * N + j0] = a00 * __expf(-dist[(size_t)i0 * N + j0]);
    S[(size_t)i0 * N + j1] = a01 * __expf(-dist[(size_t)i0 * N + j1]);
    S[(size_t)i1 * N + j0] = a10 * __expf(-dist[(size_t)i1 * N + j0]);
    S[(size_t)i1 * N + j1] = a11 * __expf(-dist[(size_t)i1 * N + j1]);
}

// ---------------- softmax + top-32 per row; one wave per row (r7 known-good) ----------------
__global__ __launch_bounds__(256) void topk_kernel(float* buf)
{
    const int lane = threadIdx.x & 63;
    const int row  = blockIdx.x * 4 + (threadIdx.x >> 6);
    float* sr = buf + (size_t)row * N;

    float v[16];
#pragma unroll
    for (int c = 0; c < 4; ++c) {
        const float4 f = *(const float4*)&sr[(c * 64 + lane) * 4];
        v[c * 4 + 0] = f.x; v[c * 4 + 1] = f.y; v[c * 4 + 2] = f.z; v[c * 4 + 3] = f.w;
    }
    float m = v[0];
#pragma unroll
    for (int e = 1; e < 16; ++e) m = fmaxf(m, v[e]);
#pragma unroll
    for (int off = 1; off < 64; off <<= 1) m = fmaxf(m, __shfl_xor(m, off));
    float sum = 0.f;
#pragma unroll
    for (int e = 0; e < 16; ++e) sum += __expf(v[e] - m);
#pragma unroll
    for (int off = 1; off < 64; off <<= 1) sum += __shfl_xor(sum, off);
    const float inv = 1.0f / sum;

    unsigned long long key[16];
#pragma unroll
    for (int e = 0; e < 16; ++e) {
        const int j = (((e >> 2) * 64 + lane) * 4) + (e & 3);
        unsigned u = __float_as_uint(v[e]);
        u = (u & 0x80000000u) ? ~u : (u | 0x80000000u);
        key[e] = ((unsigned long long)u << 32) | (unsigned)(N - 1 - j);
    }
    unsigned flags = 0;
    for (int it = 0; it < 32; ++it) {
        unsigned long long best = key[0];
#pragma unroll
        for (int e = 1; e < 16; ++e) best = (key[e] > best) ? key[e] : best;
#pragma unroll
        for (int off = 1; off < 64; off <<= 1) {
            const unsigned long long o = __shfl_xor(best, off);
            if (o > best) best = o;
        }
#pragma unroll
        for (int e = 0; e < 16; ++e)
            if (key[e] == best) { flags |= 1u << e; key[e] = 0ull; }
    }
#pragma unroll
    for (int c = 0; c < 4; ++c) {
        float4 o;
        o.x = (flags & (1u << (c * 4 + 0))) ? __expf(v[c * 4 + 0] - m) * inv : 0.f;
        o.y = (flags & (1u << (c * 4 + 1))) ? __expf(v[c * 4 + 1] - m) * inv : 0.f;
        o.z = (flags & (1u << (c * 4 + 2))) ? __expf(v[c * 4 + 2] - m) * inv : 0.f;
        o.w = (flags & (1u << (c * 4 + 3))) ? __expf(v[c * 4 + 3] - m) * inv : 0.f;
        *(float4*)&sr[(c * 64 + lane) * 4] = o;
    }
}

// ---------------- pairwise gelu classifier + 3-way softmax ----------------
// 32x32 tile, d-split (17.4 KB LDS). Inner loop: TRUE vector float2 (ext_vector_type)
// over the (i0,i1) pair -> v_pk_{add,mul,fma}_f32; 4 sigmoids share ONE v_rcp via
// reciprocal-of-product (trans/eval 2 -> 1.25). t clamped at 30 so the 4-term product
// stays finite (sigma < 2^-30 ~ 0 there, the correct limit).
__global__ __launch_bounds__(256) void pair_kernel(
    const float* __restrict__ A, const float* __restrict__ B,
    const float* __restrict__ W2, const float* __restrict__ b2,
    float* __restrict__ out)
{
    __shared__ float As[32 * 17 * 4];
    __shared__ float Bs[32 * 17 * 4];
    const int tid = threadIdx.x;
    const int bi = blockIdx.y * 32, bj = blockIdx.x * 32;
    const int tx = tid & 15, ty = tid >> 4;

    const float bb0 = b2[0], bb1 = b2[1], bb2 = b2[2];
    v2f acc[2][3];                     // [jj][class], lanes = (i0, i1)
#pragma unroll
    for (int jj = 0; jj < 2; ++jj) {
        acc[jj][0] = (v2f)bb0; acc[jj][1] = (v2f)bb1; acc[jj][2] = (v2f)bb2;
    }

    const float4* As4 = (const float4*)As;
    const float4* Bs4 = (const float4*)Bs;
    const v2f C3 = (v2f)(-0.1029434f);
    const v2f C1 = (v2f)(-2.3022082f);
    const v2f TCLAMP = (v2f)30.0f;

    for (int kk = 0; kk < D; kk += 64) {
        __syncthreads();
#pragma unroll
        for (int t = 0; t < 2; ++t) {
            const int e = t * 256 + tid;
            const int row = e >> 4, c = e & 15;
            *(float4*)&As[(row * 17 + c) * 4] = *(const float4*)&A[(size_t)(bi + row) * D + kk + c * 4];
            *(float4*)&Bs[(row * 17 + c) * 4] = *(const float4*)&B[(size_t)(bj + row) * D + kk + c * 4];
        }
        __syncthreads();

#pragma unroll 4
        for (int c = 0; c < 16; ++c) {
            const float4 a0 = As4[ty * 17 + c];
            const float4 a1 = As4[(ty + 16) * 17 + c];
            const float4 b0 = Bs4[tx * 17 + c];
            const float4 b1 = Bs4[(tx + 16) * 17 + c];
#pragma unroll
            for (int q = 0; q < 4; ++q) {
                const int dd = kk + c * 4 + q;
                const float w0 = W2[dd * 3 + 0];    // wave-uniform -> s_load
                const float w1 = W2[dd * 3 + 1];
                const float w2 = W2[dd * 3 + 2];
                v2f av;
                av.x = (q == 0) ? a0.x : (q == 1) ? a0.y : (q == 2) ? a0.z : a0.w;
                av.y = (q == 0) ? a1.x : (q == 1) ? a1.y : (q == 2) ? a1.z : a1.w;
                const float bv0 = (q == 0) ? b0.x : (q == 1) ? b0.y : (q == 2) ? b0.z : b0.w;
                const float bv1 = (q == 0) ? b1.x : (q == 1) ? b1.y : (q == 2) ? b1.z : b1.w;

                const v2f x0 = av + bv0;            // pk_add (scalar broadcasts)
                const v2f x1 = av + bv1;
                const v2f u0 = x0 * x0;             // pk_mul
                const v2f u1 = x1 * x1;
                v2f t0 = x0 * (u0 * C3 + C1);       // pk_fma + pk_mul
                v2f t1 = x1 * (u1 * C3 + C1);
                t0 = __builtin_elementwise_min(t0, TCLAMP);
                t1 = __builtin_elementwise_min(t1, TCLAMP);
                v2f e0, e1;
                e0.x = __builtin_amdgcn_exp2f(t0.x);
                e0.y = __builtin_amdgcn_exp2f(t0.y);
                e1.x = __builtin_amdgcn_exp2f(t1.x);
                e1.y = __builtin_amdgcn_exp2f(t1.y);
                const v2f d0 = e0 + 1.0f;
                const v2f d1 = e1 + 1.0f;
                const v2f dp = d0 * d1;             // {prod over j at i0, at i1}
                const float full = dp.x * dp.y;
                const float r = __builtin_amdgcn_rcpf(full);   // ONE rcp for 4 sigmoids
                v2f rxy;                            // {1/dp.x, 1/dp.y}
                rxy.x = r * dp.y;
                rxy.y = r * dp.x;
                const v2f g0 = x0 * (rxy * d1);     // x * (1/d0)
                const v2f g1 = x1 * (rxy * d0);     // x * (1/d1)
                acc[0][0] += g0 * w0;               // pk_fma
                acc[0][1] += g0 * w1;
                acc[0][2] += g0 * w2;
                acc[1][0] += g1 * w0;
                acc[1][1] += g1 * w1;
                acc[1][2] += g1 * w2;
            }
        }
    }

#pragma unroll
    for (int ii = 0; ii < 2; ++ii)
#pragma unroll
        for (int jj = 0; jj < 2; ++jj) {
            const int i = bi + ty + 16 * ii;
            const int j = bj + tx + 16 * jj;
            const float l0 = ii ? acc[jj][0].y : acc[jj][0].x;
            const float l1 = ii ? acc[jj][1].y : acc[jj][1].x;
            const float l2 = ii ? acc[jj][2].y : acc[jj][2].x;
            const float mm = fmaxf(l0, fmaxf(l1, l2));
            const float e0 = __expf(l0 - mm), e1 = __expf(l1 - mm), e2 = __expf(l2 - mm);
            const float inv2 = 1.0f / (e0 + e1 + e2);
            float* o = out + ((size_t)i * N + j) * 3;
            o[0] = e0 * inv2; o[1] = e1 * inv2; o[2] = e2 * inv2;
        }
}

extern "C" void kernel_launch(void* const* d_in, const int* in_sizes, int n_in,
                              void* d_out, int out_size, void* d_ws, size_t ws_size,
                              hipStream_t stream)
{
    const float* z    = (const float*)d_in[0];
    const float* dist = (const float*)d_in[1];
    const float* Wq   = (const float*)d_in[2];
    const float* bq   = (const float*)d_in[3];
    const float* Wk   = (const float*)d_in[4];
    const float* bk   = (const float*)d_in[5];
    const float* W1   = (const float*)d_in[6];
    const float* b1   = (const float*)d_in[7];
    const float* W2   = (const float*)d_in[8];
    const float* b2   = (const float*)d_in[9];

    float* out = (float*)d_out;
    float* ws  = (float*)d_ws;
    float* Q  = ws;
    float* K  = ws + (size_t)N * D;
    float* A  = ws + 2 * (size_t)N * D;
    float* B  = ws + 3 * (size_t)N * D;

    proj_kernel<<<N / 8, 256, 0, stream>>>(z, Wq, bq, Wk, bk, W1, b1, Q, K, A, B);
    score_kernel<<<dim3(N / 32, N / 32), 256, 0, stream>>>(Q, K, dist, out);
    topk_kernel<<<N / 4, 256, 0, stream>>>(out);
    pair_kernel<<<dim3(N / 32, N / 32), 256, 0, stream>>>(A, B, W2, b2, out + (size_t)N * N);
}

// Round 10
// 159.564 us; speedup vs baseline: 1.1213x; 1.0212x over previous
//
#include <hip/hip_runtime.h>
#include <hip/hip_fp16.h>

#define N 1024
#define D 128

// ---------------- proj: Q,K (f32) + Ah,Bh (f16) = z@{Wq,Wk,W1a,W1b} ----------------
__global__ __launch_bounds__(256) void proj_kernel(
    const float* __restrict__ z,
    const float* __restrict__ Wq, const float* __restrict__ bq,
    const float* __restrict__ Wk, const float* __restrict__ bk,
    const float* __restrict__ W1, const float* __restrict__ b1,
    float* __restrict__ Q, float* __restrict__ Kx,
    __half* __restrict__ Ah, __half* __restrict__ Bh)
{
    const int d  = threadIdx.x & (D - 1);
    const int h  = threadIdx.x >> 7;              // wave-uniform: 0 -> Q/K, 1 -> A/B
    const int r0 = blockIdx.x * 8;
    const float* __restrict__ Wa = h ? W1           : Wq;
    const float* __restrict__ Wb = h ? (W1 + D * D) : Wk;

    float acc0[8] = {0,0,0,0,0,0,0,0};
    float acc1[8] = {0,0,0,0,0,0,0,0};

    for (int c = 0; c < D / 4; ++c) {
        float4 zr[8];
#pragma unroll
        for (int r = 0; r < 8; ++r)
            zr[r] = *(const float4*)&z[(r0 + r) * D + c * 4];
#pragma unroll
        for (int q = 0; q < 4; ++q) {
            const int k = c * 4 + q;
            const float wa = Wa[k * D + d];
            const float wb = Wb[k * D + d];
#pragma unroll
            for (int r = 0; r < 8; ++r) {
                const float zv = (q == 0) ? zr[r].x : (q == 1) ? zr[r].y : (q == 2) ? zr[r].z : zr[r].w;
                acc0[r] = fmaf(zv, wa, acc0[r]);
                acc1[r] = fmaf(zv, wb, acc1[r]);
            }
        }
    }
    if (h == 0) {
        const float c0 = bq[d], c1 = bk[d];
        const float scale = 0.08838834764831845f;   // 1/sqrt(128), folded into Q
#pragma unroll
        for (int r = 0; r < 8; ++r) {
            Q [(r0 + r) * D + d] = (acc0[r] + c0) * scale;
            Kx[(r0 + r) * D + d] = acc1[r] + c1;
        }
    } else {
        const float c0 = b1[d];
#pragma unroll
        for (int r = 0; r < 8; ++r) {
            Ah[(r0 + r) * D + d] = __float2half(acc0[r] + c0);   // b1 folded
            Bh[(r0 + r) * D + d] = __float2half(acc1[r]);
        }
    }
}

// ---------------- scores: S = (Q K^T) * exp(-dist), 32x32 tile (known-good) ----------------
__global__ __launch_bounds__(256) void score_kernel(
    const float* __restrict__ Q, const float* __restrict__ Kx,
    const float* __restrict__ dist, float* __restrict__ S)
{
    __shared__ float Qs[32 * 33 * 4];
    __shared__ float Ks[32 * 33 * 4];
    const int tid = threadIdx.x;
    const int bi = blockIdx.y * 32, bj = blockIdx.x * 32;
    const int tx = tid & 15, ty = tid >> 4;

#pragma unroll
    for (int t = 0; t < 4; ++t) {
        const int e = t * 256 + tid;
        const int row = e >> 5, c = e & 31;
        *(float4*)&Qs[(row * 33 + c) * 4] = *(const float4*)&Q [(size_t)(bi + row) * D + c * 4];
        *(float4*)&Ks[(row * 33 + c) * 4] = *(const float4*)&Kx[(size_t)(bj + row) * D + c * 4];
    }
    __syncthreads();

    const float4* Qs4 = (const float4*)Qs;
    const float4* Ks4 = (const float4*)Ks;
    float a00 = 0.f, a01 = 0.f, a10 = 0.f, a11 = 0.f;

#pragma unroll 4
    for (int c = 0; c < 32; ++c) {
        const float4 q0 = Qs4[ty * 33 + c];
        const float4 q1 = Qs4[(ty + 16) * 33 + c];
        const float4 k0 = Ks4[tx * 33 + c];
        const float4 k1 = Ks4[(tx + 16) * 33 + c];
        a00 = fmaf(q0.x, k0.x, a00); a00 = fmaf(q0.y, k0.y, a00); a00 = fmaf(q0.z, k0.z, a00); a00 = fmaf(q0.w, k0.w, a00);
        a01 = fmaf(q0.x, k1.x, a01); a01 = fmaf(q0.y, k1.y, a01); a01 = fmaf(q0.z, k1.z, a01); a01 = fmaf(q0.w, k1.w, a01);
        a10 = fmaf(q1.x, k0.x, a10); a10 = fmaf(q1.y, k0.y, a10); a10 = fmaf(q1.z, k0.z, a10); a10 = fmaf(q1.w, k0.w, a10);
        a11 = fmaf(q1.x, k1.x, a11); a11 = fmaf(q1.y, k1.y, a11); a11 = fmaf(q1.z, k1.z, a11); a11 = fmaf(q1.w, k1.w, a11);
    }

    const int i0 = bi + ty, i1 = bi + ty + 16;
    const int j0 = bj + tx, j1 = bj + tx + 16;
    S[(size_t)i0 * N + j0] = a00 * __expf(-dist[(size_t)i0 * N + j0]);
    S[(size_t)i0 * N + j1] = a01 * __expf(-dist[(size_t)i0 * N + j1]);
    S[(size_t)i1 * N + j0] = a10 * __expf(-dist[(size_t)i1 * N + j0]);
    S[(size_t)i1 * N + j1] = a11 * __expf(-dist[(size_t)i1 * N + j1]);
}

// ---------------- softmax + top-32 per row; one wave per row (known-good) ----------------
__global__ __launch_bounds__(256) void topk_kernel(float* buf)
{
    const int lane = threadIdx.x & 63;
    const int row  = blockIdx.x * 4 + (threadIdx.x >> 6);
    float* sr = buf + (size_t)row * N;

    float v[16];
#pragma unroll
    for (int c = 0; c < 4; ++c) {
        const float4 f = *(const float4*)&sr[(c * 64 + lane) * 4];
        v[c * 4 + 0] = f.x; v[c * 4 + 1] = f.y; v[c * 4 + 2] = f.z; v[c * 4 + 3] = f.w;
    }
    float m = v[0];
#pragma unroll
    for (int e = 1; e < 16; ++e) m = fmaxf(m, v[e]);
#pragma unroll
    for (int off = 1; off < 64; off <<= 1) m = fmaxf(m, __shfl_xor(m, off));
    float sum = 0.f;
#pragma unroll
    for (int e = 0; e < 16; ++e) sum += __expf(v[e] - m);
#pragma unroll
    for (int off = 1; off < 64; off <<= 1) sum += __shfl_xor(sum, off);
    const float inv = 1.0f / sum;

    unsigned long long key[16];
#pragma unroll
    for (int e = 0; e < 16; ++e) {
        const int j = (((e >> 2) * 64 + lane) * 4) + (e & 3);
        unsigned u = __float_as_uint(v[e]);
        u = (u & 0x80000000u) ? ~u : (u | 0x80000000u);
        key[e] = ((unsigned long long)u << 32) | (unsigned)(N - 1 - j);
    }
    unsigned flags = 0;
    for (int it = 0; it < 32; ++it) {
        unsigned long long best = key[0];
#pragma unroll
        for (int e = 1; e < 16; ++e) best = (key[e] > best) ? key[e] : best;
#pragma unroll
        for (int off = 1; off < 64; off <<= 1) {
            const unsigned long long o = __shfl_xor(best, off);
            if (o > best) best = o;
        }
#pragma unroll
        for (int e = 0; e < 16; ++e)
            if (key[e] == best) { flags |= 1u << e; key[e] = 0ull; }
    }
#pragma unroll
    for (int c = 0; c < 4; ++c) {
        float4 o;
        o.x = (flags & (1u << (c * 4 + 0))) ? __expf(v[c * 4 + 0] - m) * inv : 0.f;
        o.y = (flags & (1u << (c * 4 + 1))) ? __expf(v[c * 4 + 1] - m) * inv : 0.f;
        o.z = (flags & (1u << (c * 4 + 2))) ? __expf(v[c * 4 + 2] - m) * inv : 0.f;
        o.w = (flags & (1u << (c * 4 + 3))) ? __expf(v[c * 4 + 3] - m) * inv : 0.f;
        *(float4*)&sr[(c * 64 + lane) * 4] = o;
    }
}

// ---------------- pairwise gelu classifier + 3-way softmax, f16x2 packed over d-pairs ----------------
// 32x32 tile, FULL D=128 resident as halves (17.4 KB, single stage, no mid barriers).
// v_pk_*_f16 for gelu math (reliable codegen), v_dot2_f32_f16 for exact-f32 class accumulation.
// W2 preconverted to half2 in LDS -> b128 broadcasts, no in-loop SMEM (no lgkmcnt(0) drains).
union H2x4 { uint4 u; __half2 h[4]; };

__device__ __forceinline__ float fdot2_acc(__half2 a, __half2 b, float c) {
#if __has_builtin(__builtin_amdgcn_fdot2)
    typedef _Float16 v2h __attribute__((ext_vector_type(2)));
    union { __half2 h; v2h v; } ua, ub;
    ua.h = a; ub.h = b;
    return __builtin_amdgcn_fdot2(ua.v, ub.v, c, false);
#else
    return fmaf(__low2float(a), __low2float(b),
           fmaf(__high2float(a), __high2float(b), c));
#endif
}

#define HP 136   // halves pitch: 272 B rows (16B-aligned), bank stride 4 -> only free 2-way alias

__global__ __launch_bounds__(256) void pair_kernel(
    const __half* __restrict__ Ah, const __half* __restrict__ Bh,
    const float* __restrict__ W2, const float* __restrict__ b2,
    float* __restrict__ out)
{
    __shared__ __align__(16) __half AsH[32 * HP];
    __shared__ __align__(16) __half BsH[32 * HP];
    __shared__ __align__(16) __half2 Wh[3][68];
    const int tid = threadIdx.x;
    const int bi = blockIdx.y * 32, bj = blockIdx.x * 32;
    const int tx = tid & 15, ty = tid >> 4;

    // stage A,B (f16) into LDS: 512+512 16B chunks
#pragma unroll
    for (int t = 0; t < 2; ++t) {
        const int e = t * 256 + tid;
        const int row = e >> 4, c = e & 15;
        *(uint4*)&AsH[row * HP + c * 8] = *(const uint4*)&Ah[(size_t)(bi + row) * D + c * 8];
        *(uint4*)&BsH[row * HP + c * 8] = *(const uint4*)&Bh[(size_t)(bj + row) * D + c * 8];
    }
    // W2 -> half2 pairs over d: Wh[cls][dp] = {W2[2dp][cls], W2[2dp+1][cls]}
    if (tid < 192) {
        const int cls = tid >> 6, dp = tid & 63;
        Wh[cls][dp] = __floats2half2_rn(W2[6 * dp + cls], W2[6 * dp + 3 + cls]);
    }
    const float bb0 = b2[0], bb1 = b2[1], bb2 = b2[2];
    __syncthreads();

    float acc[4][3];                    // [site=ii*2+jj][class]
#pragma unroll
    for (int p = 0; p < 4; ++p) { acc[p][0] = bb0; acc[p][1] = bb1; acc[p][2] = bb2; }

    const __half2 C3  = __float2half2_rn(-0.1029434f);
    const __half2 C1  = __float2half2_rn(-2.3022082f);
    const __half2 ONE = __float2half2_rn(1.0f);

#pragma unroll 4
    for (int c = 0; c < 16; ++c) {      // 16 chunks x 8 d
        H2x4 a0, a1, b0, b1, w0, w1, w2;
        a0.u = *(const uint4*)&AsH[ty * HP + c * 8];
        a1.u = *(const uint4*)&AsH[(ty + 16) * HP + c * 8];
        b0.u = *(const uint4*)&BsH[tx * HP + c * 8];
        b1.u = *(const uint4*)&BsH[(tx + 16) * HP + c * 8];
        w0.u = *(const uint4*)&Wh[0][c * 4];    // wave-uniform -> LDS broadcast
        w1.u = *(const uint4*)&Wh[1][c * 4];
        w2.u = *(const uint4*)&Wh[2][c * 4];
#pragma unroll
        for (int dp = 0; dp < 4; ++dp) {
            const __half2 aa[2] = { a0.h[dp], a1.h[dp] };
            const __half2 bb[2] = { b0.h[dp], b1.h[dp] };
            const __half2 wc0 = w0.h[dp], wc1 = w1.h[dp], wc2 = w2.h[dp];
#pragma unroll
            for (int ii = 0; ii < 2; ++ii)
#pragma unroll
                for (int jj = 0; jj < 2; ++jj) {
                    const __half2 x = __hadd2(aa[ii], bb[jj]);
                    const __half2 u = __hmul2(x, x);
                    const __half2 p = __hfma2(C3, u, C1);
                    const __half2 t = __hmul2(x, p);
                    const __half2 e = h2exp2(t);          // 2^t ; under/overflow -> 0/inf (correct limits)
                    const __half2 dn = __hadd2(e, ONE);
                    const __half2 r = h2rcp(dn);          // rcp(inf)=0 -> g=0 (correct)
                    const __half2 g = __hmul2(x, r);
                    float* l = acc[ii * 2 + jj];
                    l[0] = fdot2_acc(g, wc0, l[0]);
                    l[1] = fdot2_acc(g, wc1, l[1]);
                    l[2] = fdot2_acc(g, wc2, l[2]);
                }
        }
    }

#pragma unroll
    for (int ii = 0; ii < 2; ++ii)
#pragma unroll
        for (int jj = 0; jj < 2; ++jj) {
            const int i = bi + ty + 16 * ii;
            const int j = bj + tx + 16 * jj;
            const float* l = acc[ii * 2 + jj];
            const float mm = fmaxf(l[0], fmaxf(l[1], l[2]));
            const float e0 = __expf(l[0] - mm), e1 = __expf(l[1] - mm), e2 = __expf(l[2] - mm);
            const float inv2 = 1.0f / (e0 + e1 + e2);
            float* o = out + ((size_t)i * N + j) * 3;
            o[0] = e0 * inv2; o[1] = e1 * inv2; o[2] = e2 * inv2;
        }
}

extern "C" void kernel_launch(void* const* d_in, const int* in_sizes, int n_in,
                              void* d_out, int out_size, void* d_ws, size_t ws_size,
                              hipStream_t stream)
{
    const float* z    = (const float*)d_in[0];
    const float* dist = (const float*)d_in[1];
    const float* Wq   = (const float*)d_in[2];
    const float* bq   = (const float*)d_in[3];
    const float* Wk   = (const float*)d_in[4];
    const float* bk   = (const float*)d_in[5];
    const float* W1   = (const float*)d_in[6];
    const float* b1   = (const float*)d_in[7];
    const float* W2   = (const float*)d_in[8];
    const float* b2   = (const float*)d_in[9];

    float* out = (float*)d_out;
    float* ws  = (float*)d_ws;
    float*  Q  = ws;
    float*  K  = ws + (size_t)N * D;
    __half* Ah = (__half*)(ws + 2 * (size_t)N * D);
    __half* Bh = Ah + (size_t)N * D;

    proj_kernel<<<N / 8, 256, 0, stream>>>(z, Wq, bq, Wk, bk, W1, b1, Q, K, Ah, Bh);
    score_kernel<<<dim3(N / 32, N / 32), 256, 0, stream>>>(Q, K, dist, out);
    topk_kernel<<<N / 4, 256, 0, stream>>>(out);
    pair_kernel<<<dim3(N / 32, N / 32), 256, 0, stream>>>(Ah, Bh, W2, b2, out + (size_t)N * N);
}